// Round 3
// baseline (1015.276 us; speedup 1.0000x reference)
//
#include <hip/hip_runtime.h>
#include <math.h>

#define HH 16
#define SS 2048
#define DD 128
#define NROWS (HH * SS)            // 32768
#define OUTSZ (HH * SS * DD)       // 4194304 elems per tensor

typedef __attribute__((ext_vector_type(8))) short bf16x8;
typedef __attribute__((ext_vector_type(4))) float f32x4;
typedef __attribute__((ext_vector_type(8))) unsigned short u16x8;

#define MFMA16(a, b, c) __builtin_amdgcn_mfma_f32_16x16x32_bf16(a, b, c, 0, 0, 0)

__device__ __forceinline__ unsigned short f2bf(float f) {
    unsigned u = __float_as_uint(f);
    return (unsigned short)((u + 0x7FFFu + ((u >> 16) & 1u)) >> 16);   // RNE
}
__device__ __forceinline__ bf16x8 negf(bf16x8 a) {
    bf16x8 r;
#pragma unroll
    for (int j = 0; j < 8; ++j) r[j] = (short)(a[j] ^ (short)0x8000);
    return r;
}

struct ClinPtrs {
    const float* xr; const float* xi;
    const float* gr; const float* gi;     // GATE only
    const float* wr; const float* wi;
    const float* br; const float* bi;
    const float* per; const float* pei;   // may be null
    void* yr; void* yi;
    int outbf;                            // 1: bf16 out, 0: fp32 out
};

// ---------------------------------------------------------------------------
// MFMA complex linear, fused multi-projection + N-split.
// grid (NROWS/64, nproj, 2). blockIdx.y selects pointer set, z selects output
// column half (stages only 64 W rows -> 35 KB LDS -> 4 blocks/CU).
// GATE: x = (xr,xi) (*) (gr,gi) complex product at fragment build.
// ---------------------------------------------------------------------------
template <bool GATE>
__global__ __launch_bounds__(256, 3)
void clin_mfma(ClinPtrs P0, ClinPtrs P1, ClinPtrs P2, ClinPtrs P3) {
    __shared__ unsigned short wsh[2][64][136];   // 34816 B

    const int py = blockIdx.y;
    const ClinPtrs P = (py == 0) ? P0 : (py == 1) ? P1 : (py == 2) ? P2 : P3;
    const int c0 = blockIdx.z * 64;              // output-column half

    const int t = threadIdx.x;
    // ---- stage W rows c0..c0+63 fp32->bf16 (2048 groups of 8) ----
#pragma unroll
    for (int u = 0; u < 8; ++u) {
        const int f = t + 256 * u;
        const int c = f >> 10;
        const int rem = f & 1023;
        const int row = rem >> 4;
        const int g8 = (rem & 15) * 8;
        const float* src = (c ? P.wi : P.wr) + (long)(c0 + row) * DD + g8;
        const float4 a = *(const float4*)src;
        const float4 b = *(const float4*)(src + 4);
        unsigned short tmp[8] = {f2bf(a.x), f2bf(a.y), f2bf(a.z), f2bf(a.w),
                                 f2bf(b.x), f2bf(b.y), f2bf(b.z), f2bf(b.w)};
        *(u16x8*)&wsh[c][row][g8] = *(u16x8*)tmp;
    }

    const int w = t >> 6, lane = t & 63;
    const int lm = lane & 15, quad = lane >> 4;
    const long m0 = (long)blockIdx.x * 64 + w * 16;

    // ---- A fragments: rows m0+lm, k = dk*32 + quad*8 + j ----
    bf16x8 xrf[4], xif[4];
    {
        const long rbase = (m0 + lm) * DD;
#pragma unroll
        for (int dk = 0; dk < 4; ++dk) {
            const long o = rbase + dk * 32 + quad * 8;
            const float4 a0 = *(const float4*)(P.xr + o);
            const float4 a1 = *(const float4*)(P.xr + o + 4);
            const float4 b0 = *(const float4*)(P.xi + o);
            const float4 b1 = *(const float4*)(P.xi + o + 4);
            float fr[8] = {a0.x, a0.y, a0.z, a0.w, a1.x, a1.y, a1.z, a1.w};
            float fi[8] = {b0.x, b0.y, b0.z, b0.w, b1.x, b1.y, b1.z, b1.w};
            if (GATE) {
                const float4 c0v = *(const float4*)(P.gr + o);
                const float4 c1v = *(const float4*)(P.gr + o + 4);
                const float4 d0v = *(const float4*)(P.gi + o);
                const float4 d1v = *(const float4*)(P.gi + o + 4);
                const float ur[8] = {c0v.x, c0v.y, c0v.z, c0v.w, c1v.x, c1v.y, c1v.z, c1v.w};
                const float ui[8] = {d0v.x, d0v.y, d0v.z, d0v.w, d1v.x, d1v.y, d1v.z, d1v.w};
#pragma unroll
                for (int j = 0; j < 8; ++j) {
                    const float pr = fr[j] * ur[j] - fi[j] * ui[j];
                    const float pi = fr[j] * ui[j] + fi[j] * ur[j];
                    fr[j] = pr; fi[j] = pi;
                }
            }
#pragma unroll
            for (int j = 0; j < 8; ++j) {
                xrf[dk][j] = (short)f2bf(fr[j]);
                xif[dk][j] = (short)f2bf(fi[j]);
            }
        }
    }

    f32x4 Or[4], Oi[4];
    const f32x4 z = {0.f, 0.f, 0.f, 0.f};
#pragma unroll
    for (int nt = 0; nt < 4; ++nt) { Or[nt] = z; Oi[nt] = z; }

    __syncthreads();

#pragma unroll
    for (int dk = 0; dk < 4; ++dk) {
        const bf16x8 nxi = negf(xif[dk]);
        const int off = dk * 32 + quad * 8;
#pragma unroll
        for (int nt = 0; nt < 4; ++nt) {
            const bf16x8 wrf = *(bf16x8*)&wsh[0][nt * 16 + lm][off];
            const bf16x8 wif = *(bf16x8*)&wsh[1][nt * 16 + lm][off];
            Or[nt] = MFMA16(xrf[dk], wrf, Or[nt]);
            Or[nt] = MFMA16(nxi,     wif, Or[nt]);
            Oi[nt] = MFMA16(xrf[dk], wif, Oi[nt]);
            Oi[nt] = MFMA16(xif[dk], wrf, Oi[nt]);
        }
    }

    // ---- epilogue: C layout row = quad*4+reg, col = c0 + nt*16 + lm ----
#pragma unroll
    for (int nt = 0; nt < 4; ++nt) {
        const int c = c0 + nt * 16 + lm;
        const float bra = P.br[c], bia = P.bi[c];
#pragma unroll
        for (int reg = 0; reg < 4; ++reg) {
            const long R = m0 + quad * 4 + reg;
            float vr = Or[nt][reg] + bra;
            float vi = Oi[nt][reg] + bia;
            if (P.per != nullptr) {
                vr += P.per[R * DD + c];
                vi += P.pei[R * DD + c];
            }
            if (P.outbf) {
                ((unsigned short*)P.yr)[R * DD + c] = f2bf(vr);
                ((unsigned short*)P.yi)[R * DD + c] = f2bf(vi);
            } else {
                ((float*)P.yr)[R * DD + c] = vr;
                ((float*)P.yi)[R * DD + c] = vi;
            }
        }
    }
}

// ---------------------------------------------------------------------------
// MFMA flash attention, complex-magnitude scores. bf16 q,k,v inputs.
// 1D grid 512 blocks, XCD-swizzled so head h lives on XCD h%8 (L2 reuse:
// per-XCD K/V working set = 2 heads = 4 MiB ~ L2). 4 waves, wave w owns
// 16 q rows. Register-prefetch double-stages the next K/V tile so global
// latency hides under MFMA+softmax.
// ---------------------------------------------------------------------------
__global__ __launch_bounds__(256, 3)
void attn_mfma(const unsigned short* __restrict__ qr, const unsigned short* __restrict__ qi,
               const unsigned short* __restrict__ kr, const unsigned short* __restrict__ ki,
               const unsigned short* __restrict__ vr, const unsigned short* __restrict__ vi,
               float* __restrict__ out_r, float* __restrict__ out_i) {
    __shared__ unsigned short ks[2][32][136];   // 17408 B
    __shared__ unsigned short vt[2][DD][40];    // 20480 B (V transposed [d][k])
    __shared__ unsigned short ps[64][40];       //  5120 B (P, bf16)

    const int t = threadIdx.x;
    const int w = t >> 6, lane = t & 63;
    const int lm = lane & 15, quad = lane >> 4;

    // XCD-locality swizzle: bid = xcd + 8*(qt + 32*(h/8)), xcd = h%8
    const int bid = blockIdx.x;
    const int xcd = bid & 7;
    const int kk_ = bid >> 3;
    const int qt = kk_ & 31;
    const int h  = xcd + 8 * (kk_ >> 5);
    const long hbase = (long)h * SS * DD;
    const int q0 = qt * 64;
    const float scale = 0.08838834764831845f;   // 128^-0.5

    // ---- resident Q fragments (A layout) ----
    bf16x8 qrf[4], qif[4], nqrf[4];
    {
        const long rb = hbase + (long)(q0 + w * 16 + lm) * DD;
#pragma unroll
        for (int dk = 0; dk < 4; ++dk) {
            qrf[dk] = *(const bf16x8*)(qr + rb + dk * 32 + quad * 8);
            qif[dk] = *(const bf16x8*)(qi + rb + dk * 32 + quad * 8);
            nqrf[dk] = negf(qrf[dk]);
        }
    }

    f32x4 Or[8], Oi[8];
    const f32x4 z = {0.f, 0.f, 0.f, 0.f};
#pragma unroll
    for (int nt = 0; nt < 8; ++nt) { Or[nt] = z; Oi[nt] = z; }
    float m_st[4] = {-1e30f, -1e30f, -1e30f, -1e30f};
    float l_st[4] = {0.f, 0.f, 0.f, 0.f};

    // prefetch registers
    u16x8 kreg[4];
    u16x8 vra[2], vrb[2];

    auto load_tile = [&](int k0) {
#pragma unroll
        for (int u = 0; u < 4; ++u) {
            const int f = t + 256 * u;
            const int c = f >> 9;
            const int rem = f & 511;
            const int r = rem >> 4;
            const int g8 = (rem & 15) * 8;
            const unsigned short* src = (c ? ki : kr) + hbase + (long)(k0 + r) * DD + g8;
            kreg[u] = *(const u16x8*)src;
        }
#pragma unroll
        for (int u = 0; u < 2; ++u) {
            const int p = t + 256 * u;
            const int c = p >> 8;
            const int rem = p & 255;
            const int s2 = (rem & 15) * 2;
            const int d8 = (rem >> 4) * 8;
            const unsigned short* src = (c ? vi : vr) + hbase + (long)(k0 + s2) * DD + d8;
            vra[u] = *(const u16x8*)src;
            vrb[u] = *(const u16x8*)(src + DD);
        }
    };
    auto store_tile = [&]() {
#pragma unroll
        for (int u = 0; u < 4; ++u) {
            const int f = t + 256 * u;
            const int c = f >> 9;
            const int rem = f & 511;
            const int r = rem >> 4;
            const int g8 = (rem & 15) * 8;
            *(u16x8*)&ks[c][r][g8] = kreg[u];
        }
#pragma unroll
        for (int u = 0; u < 2; ++u) {
            const int p = t + 256 * u;
            const int c = p >> 8;
            const int rem = p & 255;
            const int s2 = (rem & 15) * 2;
            const int d8 = (rem >> 4) * 8;
#pragma unroll
            for (int j = 0; j < 8; ++j) {
                const unsigned val = (unsigned)(unsigned short)vra[u][j] |
                                     ((unsigned)(unsigned short)vrb[u][j] << 16);
                *(unsigned*)&vt[c][d8 + j][s2] = val;
            }
        }
    };

    load_tile(0);

    for (int kt = 0; kt < SS / 32; ++kt) {
        __syncthreads();               // all waves done reading prev LDS tile
        store_tile();                  // (waits vmcnt on prefetch regs)
        __syncthreads();               // LDS tile ready
        if (kt + 1 < SS / 32) load_tile((kt + 1) * 32);   // prefetch next

        // ---- scores: two 16x16 tiles (k cols 0-15, 16-31) ----
        f32x4 sr0 = z, sr1 = z, si0 = z, si1 = z;
#pragma unroll
        for (int dk = 0; dk < 4; ++dk) {
            const int off = dk * 32 + quad * 8;
            const bf16x8 kr0 = *(bf16x8*)&ks[0][lm][off];
            const bf16x8 ki0 = *(bf16x8*)&ks[1][lm][off];
            const bf16x8 kr1 = *(bf16x8*)&ks[0][16 + lm][off];
            const bf16x8 ki1 = *(bf16x8*)&ks[1][16 + lm][off];
            sr0 = MFMA16(qrf[dk], kr0, sr0);  sr0 = MFMA16(qif[dk], ki0, sr0);
            si0 = MFMA16(qif[dk], kr0, si0);  si0 = MFMA16(nqrf[dk], ki0, si0);
            sr1 = MFMA16(qrf[dk], kr1, sr1);  sr1 = MFMA16(qif[dk], ki1, sr1);
            si1 = MFMA16(qif[dk], kr1, si1);  si1 = MFMA16(nqrf[dk], ki1, si1);
        }

        // ---- online softmax, per reg (= per q-row of this lane group) ----
#pragma unroll
        for (int reg = 0; reg < 4; ++reg) {
            const float s0 = __builtin_amdgcn_sqrtf(
                fmaf(sr0[reg], sr0[reg], fmaf(si0[reg], si0[reg], 1e-8f))) * scale;
            const float s1 = __builtin_amdgcn_sqrtf(
                fmaf(sr1[reg], sr1[reg], fmaf(si1[reg], si1[reg], 1e-8f))) * scale;
            float rm = fmaxf(s0, s1);
#pragma unroll
            for (int off = 1; off < 16; off <<= 1) rm = fmaxf(rm, __shfl_xor(rm, off));
            if (__ballot(rm > m_st[reg])) {        // wave-uniform lazy rescale
                const float mnew = fmaxf(m_st[reg], rm);
                const float al = __expf(m_st[reg] - mnew);
                m_st[reg] = mnew;
                l_st[reg] *= al;
#pragma unroll
                for (int nt = 0; nt < 8; ++nt) { Or[nt][reg] *= al; Oi[nt][reg] *= al; }
            }
            const float p0 = __expf(s0 - m_st[reg]);
            const float p1 = __expf(s1 - m_st[reg]);
            l_st[reg] += p0 + p1;
            ps[w * 16 + quad * 4 + reg][lm]      = f2bf(p0);
            ps[w * 16 + quad * 4 + reg][16 + lm] = f2bf(p1);
        }

        // ---- PV: P (A layout via LDS, intra-wave) x V^T tiles ----
        const bf16x8 pf = *(bf16x8*)&ps[w * 16 + lm][quad * 8];
#pragma unroll
        for (int nt = 0; nt < 8; ++nt) {
            const bf16x8 vrf = *(bf16x8*)&vt[0][nt * 16 + lm][quad * 8];
            const bf16x8 vif = *(bf16x8*)&vt[1][nt * 16 + lm][quad * 8];
            Or[nt] = MFMA16(pf, vrf, Or[nt]);
            Oi[nt] = MFMA16(pf, vif, Oi[nt]);
        }
    }

    // ---- finalize: reduce l across 16-lane group, scale, store ----
    float linv[4];
#pragma unroll
    for (int reg = 0; reg < 4; ++reg) {
        float l = l_st[reg];
#pragma unroll
        for (int off = 1; off < 16; off <<= 1) l += __shfl_xor(l, off);
        linv[reg] = 1.f / l;
    }
    const long ob = hbase + (long)(q0 + w * 16) * DD;
#pragma unroll
    for (int nt = 0; nt < 8; ++nt) {
        const int c = nt * 16 + lm;
#pragma unroll
        for (int reg = 0; reg < 4; ++reg) {
            const long R = ob + (long)(quad * 4 + reg) * DD + c;
            out_r[R] = Or[nt][reg] * linv[reg];
            out_i[R] = Oi[nt][reg] * linv[reg];
        }
    }
}

// ---------------------------------------------------------------------------
extern "C" void kernel_launch(void* const* d_in, const int* in_sizes, int n_in,
                              void* d_out, int out_size, void* d_ws, size_t ws_size,
                              hipStream_t stream) {
    const float* q_r    = (const float*)d_in[0];
    const float* q_i    = (const float*)d_in[1];
    const float* k_r    = (const float*)d_in[2];
    const float* k_i    = (const float*)d_in[3];
    const float* v_r    = (const float*)d_in[4];
    const float* v_i    = (const float*)d_in[5];
    const float* pe_q_r = (const float*)d_in[6];
    const float* pe_q_i = (const float*)d_in[7];
    const float* pe_k_r = (const float*)d_in[8];
    const float* pe_k_i = (const float*)d_in[9];
    const float* qw_r = (const float*)d_in[10];
    const float* qw_i = (const float*)d_in[11];
    const float* qb_r = (const float*)d_in[12];
    const float* qb_i = (const float*)d_in[13];
    const float* kw_r = (const float*)d_in[14];
    const float* kw_i = (const float*)d_in[15];
    const float* kb_r = (const float*)d_in[16];
    const float* kb_i = (const float*)d_in[17];
    const float* vw_r = (const float*)d_in[18];
    const float* vw_i = (const float*)d_in[19];
    const float* vb_r = (const float*)d_in[20];
    const float* vb_i = (const float*)d_in[21];
    const float* gw_r = (const float*)d_in[22];
    const float* gw_i = (const float*)d_in[23];
    const float* gb_r = (const float*)d_in[24];
    const float* gb_i = (const float*)d_in[25];
    const float* ow_r = (const float*)d_in[26];
    const float* ow_i = (const float*)d_in[27];
    const float* ob_r = (const float*)d_in[28];
    const float* ob_i = (const float*)d_in[29];

    float* out_r = (float*)d_out;
    float* out_i = out_r + (long)OUTSZ;
    float* g_r   = out_r + 2L * OUTSZ;
    float* g_i   = out_r + 3L * OUTSZ;

    unsigned short* ws = (unsigned short*)d_ws;   // bf16 slots 0..5 (48 MiB)
    unsigned short* pqr = ws + 0L * OUTSZ;
    unsigned short* pqi = ws + 1L * OUTSZ;
    unsigned short* pkr = ws + 2L * OUTSZ;
    unsigned short* pki = ws + 3L * OUTSZ;
    unsigned short* pvr = ws + 4L * OUTSZ;
    unsigned short* pvi = ws + 5L * OUTSZ;
    float* a_r = (float*)(ws + 6L * OUTSZ);       // fp32 attn out (32 MiB)
    float* a_i = a_r + (long)OUTSZ;

    const dim3 blk(256);

    ClinPtrs P0 = {q_r, q_i, nullptr, nullptr, qw_r, qw_i, qb_r, qb_i,
                   pe_q_r, pe_q_i, pqr, pqi, 1};
    ClinPtrs P1 = {k_r, k_i, nullptr, nullptr, kw_r, kw_i, kb_r, kb_i,
                   pe_k_r, pe_k_i, pkr, pki, 1};
    ClinPtrs P2 = {v_r, v_i, nullptr, nullptr, vw_r, vw_i, vb_r, vb_i,
                   nullptr, nullptr, pvr, pvi, 1};
    ClinPtrs P3 = {q_r, q_i, nullptr, nullptr, gw_r, gw_i, gb_r, gb_i,
                   nullptr, nullptr, g_r, g_i, 0};

    // all 4 projections in one launch: grid (512, proj, col-half)
    clin_mfma<false><<<dim3(NROWS / 64, 4, 2), blk, 0, stream>>>(P0, P1, P2, P3);

    // flash attention -> a_r, a_i in workspace
    attn_mfma<<<dim3((SS / 64) * HH), blk, 0, stream>>>(
        pqr, pqi, pkr, pki, pvr, pvi, a_r, a_i);

    // gate + o-projection: x = g (*) a, write final out (no aliasing)
    ClinPtrs PF = {g_r, g_i, a_r, a_i, ow_r, ow_i, ob_r, ob_i,
                   nullptr, nullptr, out_r, out_i, 0};
    clin_mfma<true><<<dim3(NROWS / 64, 1, 2), blk, 0, stream>>>(PF, PF, PF, PF);
}

// Round 4
// 617.145 us; speedup vs baseline: 1.6451x; 1.6451x over previous
//
#include <hip/hip_runtime.h>
#include <math.h>

#define HH 16
#define SS 2048
#define DD 128
#define NROWS (HH * SS)            // 32768
#define OUTSZ (HH * SS * DD)       // 4194304 elems per tensor

typedef __attribute__((ext_vector_type(8))) short bf16x8;
typedef __attribute__((ext_vector_type(4))) float f32x4;
typedef __attribute__((ext_vector_type(8))) unsigned short u16x8;

#define MFMA16(a, b, c) __builtin_amdgcn_mfma_f32_16x16x32_bf16(a, b, c, 0, 0, 0)

__device__ __forceinline__ unsigned short f2bf(float f) {
    unsigned u = __float_as_uint(f);
    return (unsigned short)((u + 0x7FFFu + ((u >> 16) & 1u)) >> 16);   // RNE
}
__device__ __forceinline__ bf16x8 negf(bf16x8 a) {
    bf16x8 r;
#pragma unroll
    for (int j = 0; j < 8; ++j) r[j] = (short)(a[j] ^ (short)0x8000);
    return r;
}

struct ClinPtrs {
    const float* xr; const float* xi;
    const float* gr; const float* gi;     // GATE only
    const float* wr; const float* wi;
    const float* br; const float* bi;
    const float* per; const float* pei;   // may be null
    void* yr; void* yi;
    int outbf;                            // 1: bf16 out, 0: fp32 out
};

// ---------------------------------------------------------------------------
// MFMA complex linear. 512 thr = 8 waves, 128 rows/block, full 128 cols.
// grid (NROWS/128, nproj). W (both comps) staged bf16 in LDS once per block.
// GATE: x = (xr,xi) (*) (gr,gi) complex product at fragment build.
// In-place final proj is safe: each wave reads its 16-row slab into frags
// before its own epilogue stores; slabs are wave-disjoint.
// ---------------------------------------------------------------------------
template <bool GATE>
__global__ __launch_bounds__(512, 2)
void clin_mfma(ClinPtrs P0, ClinPtrs P1, ClinPtrs P2, ClinPtrs P3) {
    __shared__ unsigned short wsh[2][DD][136];   // 69632 B

    const int py = blockIdx.y;
    const ClinPtrs P = (py == 0) ? P0 : (py == 1) ? P1 : (py == 2) ? P2 : P3;

    const int t = threadIdx.x;
    // ---- stage W fp32->bf16 (4096 groups of 8) ----
#pragma unroll
    for (int u = 0; u < 8; ++u) {
        const int f = t + 512 * u;
        const int c = f >> 11;
        const int rem = f & 2047;
        const int row = rem >> 4;
        const int g8 = (rem & 15) * 8;
        const float* src = (c ? P.wi : P.wr) + (long)row * DD + g8;
        const float4 a = *(const float4*)src;
        const float4 b = *(const float4*)(src + 4);
        unsigned short tmp[8] = {f2bf(a.x), f2bf(a.y), f2bf(a.z), f2bf(a.w),
                                 f2bf(b.x), f2bf(b.y), f2bf(b.z), f2bf(b.w)};
        *(u16x8*)&wsh[c][row][g8] = *(u16x8*)tmp;
    }

    const int w = t >> 6, lane = t & 63;
    const int lm = lane & 15, quad = lane >> 4;
    const long m0 = (long)blockIdx.x * 128 + w * 16;

    // ---- A fragments: rows m0+lm, k = dk*32 + quad*8 + j ----
    bf16x8 xrf[4], xif[4];
    {
        const long rbase = (m0 + lm) * DD;
#pragma unroll
        for (int dk = 0; dk < 4; ++dk) {
            const long o = rbase + dk * 32 + quad * 8;
            const float4 a0 = *(const float4*)(P.xr + o);
            const float4 a1 = *(const float4*)(P.xr + o + 4);
            const float4 b0 = *(const float4*)(P.xi + o);
            const float4 b1 = *(const float4*)(P.xi + o + 4);
            float fr[8] = {a0.x, a0.y, a0.z, a0.w, a1.x, a1.y, a1.z, a1.w};
            float fi[8] = {b0.x, b0.y, b0.z, b0.w, b1.x, b1.y, b1.z, b1.w};
            if (GATE) {
                const float4 c0v = *(const float4*)(P.gr + o);
                const float4 c1v = *(const float4*)(P.gr + o + 4);
                const float4 d0v = *(const float4*)(P.gi + o);
                const float4 d1v = *(const float4*)(P.gi + o + 4);
                const float ur[8] = {c0v.x, c0v.y, c0v.z, c0v.w, c1v.x, c1v.y, c1v.z, c1v.w};
                const float ui[8] = {d0v.x, d0v.y, d0v.z, d0v.w, d1v.x, d1v.y, d1v.z, d1v.w};
#pragma unroll
                for (int j = 0; j < 8; ++j) {
                    const float pr = fr[j] * ur[j] - fi[j] * ui[j];
                    const float pi = fr[j] * ui[j] + fi[j] * ur[j];
                    fr[j] = pr; fi[j] = pi;
                }
            }
#pragma unroll
            for (int j = 0; j < 8; ++j) {
                xrf[dk][j] = (short)f2bf(fr[j]);
                xif[dk][j] = (short)f2bf(fi[j]);
            }
        }
    }

    f32x4 Or[8], Oi[8];
    const f32x4 z = {0.f, 0.f, 0.f, 0.f};
#pragma unroll
    for (int nt = 0; nt < 8; ++nt) { Or[nt] = z; Oi[nt] = z; }

    __syncthreads();

#pragma unroll
    for (int dk = 0; dk < 4; ++dk) {
        const bf16x8 nxi = negf(xif[dk]);
        const int off = dk * 32 + quad * 8;
#pragma unroll
        for (int nt = 0; nt < 8; ++nt) {
            const bf16x8 wrf = *(bf16x8*)&wsh[0][nt * 16 + lm][off];
            const bf16x8 wif = *(bf16x8*)&wsh[1][nt * 16 + lm][off];
            Or[nt] = MFMA16(xrf[dk], wrf, Or[nt]);
            Or[nt] = MFMA16(nxi,     wif, Or[nt]);
            Oi[nt] = MFMA16(xrf[dk], wif, Oi[nt]);
            Oi[nt] = MFMA16(xif[dk], wrf, Oi[nt]);
        }
    }

    // ---- epilogue: C layout row = quad*4+reg, col = nt*16 + lm ----
#pragma unroll
    for (int nt = 0; nt < 8; ++nt) {
        const int c = nt * 16 + lm;
        const float bra = P.br[c], bia = P.bi[c];
#pragma unroll
        for (int reg = 0; reg < 4; ++reg) {
            const long R = m0 + quad * 4 + reg;
            float vr = Or[nt][reg] + bra;
            float vi = Oi[nt][reg] + bia;
            if (P.per != nullptr) {
                vr += P.per[R * DD + c];
                vi += P.pei[R * DD + c];
            }
            if (P.outbf) {
                ((unsigned short*)P.yr)[R * DD + c] = f2bf(vr);
                ((unsigned short*)P.yi)[R * DD + c] = f2bf(vi);
            } else {
                ((float*)P.yr)[R * DD + c] = vr;
                ((float*)P.yi)[R * DD + c] = vi;
            }
        }
    }
}

// ---------------------------------------------------------------------------
// MFMA flash attention, complex-magnitude scores. bf16 q,k,v inputs.
// 512 thr = 8 waves, Bq=128 (wave w owns q rows q0+w*16..+15), Bk=32.
// grid 256 blocks 1D, XCD-swizzled: all 16 q-blocks of head h on XCD h%8
// (per-XCD K/V working set = 2 heads = 4 MiB ~ L2). Staging is direct
// load->LDS (NO cross-iteration register prefetch -- R3 showed that
// spills/scratch-thrashes). K row-major LDS; V transposed; P via LDS.
// ---------------------------------------------------------------------------
__global__ __launch_bounds__(512, 2)
void attn_mfma(const unsigned short* __restrict__ qr, const unsigned short* __restrict__ qi,
               const unsigned short* __restrict__ kr, const unsigned short* __restrict__ ki,
               const unsigned short* __restrict__ vr, const unsigned short* __restrict__ vi,
               float* __restrict__ out_r, float* __restrict__ out_i) {
    __shared__ unsigned short ks[2][32][136];   // 17408 B
    __shared__ unsigned short vt[2][DD][40];    // 20480 B (V transposed [d][k])
    __shared__ unsigned short ps[128][40];      // 10240 B (P, bf16)

    const int t = threadIdx.x;
    const int w = t >> 6, lane = t & 63;
    const int lm = lane & 15, quad = lane >> 4;

    // XCD swizzle: xcd = bid%8; head h = xcd + 8*(rr>>4); qt = rr&15
    const int bid = blockIdx.x;
    const int xcd = bid & 7;
    const int rr = bid >> 3;          // 0..31
    const int qt = rr & 15;
    const int h  = xcd + 8 * (rr >> 4);
    const long hbase = (long)h * SS * DD;
    const int q0 = qt * 128;
    const float scale = 0.08838834764831845f;   // 128^-0.5

    // ---- resident Q fragments (A layout), 16 rows per wave ----
    bf16x8 qrf[4], qif[4], nqrf[4];
    {
        const long rb = hbase + (long)(q0 + w * 16 + lm) * DD;
#pragma unroll
        for (int dk = 0; dk < 4; ++dk) {
            qrf[dk] = *(const bf16x8*)(qr + rb + dk * 32 + quad * 8);
            qif[dk] = *(const bf16x8*)(qi + rb + dk * 32 + quad * 8);
            nqrf[dk] = negf(qrf[dk]);
        }
    }

    f32x4 Or[8], Oi[8];
    const f32x4 z = {0.f, 0.f, 0.f, 0.f};
#pragma unroll
    for (int nt = 0; nt < 8; ++nt) { Or[nt] = z; Oi[nt] = z; }
    float m_st[4] = {-1e30f, -1e30f, -1e30f, -1e30f};
    float l_st[4] = {0.f, 0.f, 0.f, 0.f};

    for (int kt = 0; kt < SS / 32; ++kt) {
        const int k0 = kt * 32;
        __syncthreads();   // prev-iter reads of ks/vt done
        // ---- stage K (row-major bf16): 1024 groups over 512 threads ----
#pragma unroll
        for (int u = 0; u < 2; ++u) {
            const int f = t + 512 * u;
            const int c = f >> 9;
            const int rem = f & 511;
            const int r = rem >> 4;
            const int g8 = (rem & 15) * 8;
            const unsigned short* src = (c ? ki : kr) + hbase + (long)(k0 + r) * DD + g8;
            *(u16x8*)&ks[c][r][g8] = *(const u16x8*)src;
        }
        // ---- stage V transposed: vt[c][d][k], 512 pair-groups ----
        {
            const int p = t;
            const int c = p >> 8;
            const int rem = p & 255;
            const int s2 = (rem & 15) * 2;
            const int d8 = (rem >> 4) * 8;
            const unsigned short* src = (c ? vi : vr) + hbase + (long)(k0 + s2) * DD + d8;
            const u16x8 a = *(const u16x8*)src;
            const u16x8 b = *(const u16x8*)(src + DD);
#pragma unroll
            for (int j = 0; j < 8; ++j) {
                const unsigned val = (unsigned)(unsigned short)a[j] |
                                     ((unsigned)(unsigned short)b[j] << 16);
                *(unsigned*)&vt[c][d8 + j][s2] = val;
            }
        }
        __syncthreads();

        // ---- scores: two 16x16 tiles (k cols 0-15, 16-31) ----
        f32x4 sr0 = z, sr1 = z, si0 = z, si1 = z;
#pragma unroll
        for (int dk = 0; dk < 4; ++dk) {
            const int off = dk * 32 + quad * 8;
            const bf16x8 kr0 = *(bf16x8*)&ks[0][lm][off];
            const bf16x8 ki0 = *(bf16x8*)&ks[1][lm][off];
            const bf16x8 kr1 = *(bf16x8*)&ks[0][16 + lm][off];
            const bf16x8 ki1 = *(bf16x8*)&ks[1][16 + lm][off];
            sr0 = MFMA16(qrf[dk], kr0, sr0);  sr0 = MFMA16(qif[dk], ki0, sr0);
            si0 = MFMA16(qif[dk], kr0, si0);  si0 = MFMA16(nqrf[dk], ki0, si0);
            sr1 = MFMA16(qrf[dk], kr1, sr1);  sr1 = MFMA16(qif[dk], ki1, sr1);
            si1 = MFMA16(qif[dk], kr1, si1);  si1 = MFMA16(nqrf[dk], ki1, si1);
        }

        // ---- online softmax, per reg (= per q-row of this lane group) ----
#pragma unroll
        for (int reg = 0; reg < 4; ++reg) {
            const float s0 = __builtin_amdgcn_sqrtf(
                fmaf(sr0[reg], sr0[reg], fmaf(si0[reg], si0[reg], 1e-8f))) * scale;
            const float s1 = __builtin_amdgcn_sqrtf(
                fmaf(sr1[reg], sr1[reg], fmaf(si1[reg], si1[reg], 1e-8f))) * scale;
            float rm = fmaxf(s0, s1);
#pragma unroll
            for (int off = 1; off < 16; off <<= 1) rm = fmaxf(rm, __shfl_xor(rm, off));
            if (__ballot(rm > m_st[reg])) {        // wave-uniform lazy rescale
                const float mnew = fmaxf(m_st[reg], rm);
                const float al = __expf(m_st[reg] - mnew);
                m_st[reg] = mnew;
                l_st[reg] *= al;
#pragma unroll
                for (int nt = 0; nt < 8; ++nt) { Or[nt][reg] *= al; Oi[nt][reg] *= al; }
            }
            const float p0 = __expf(s0 - m_st[reg]);
            const float p1 = __expf(s1 - m_st[reg]);
            l_st[reg] += p0 + p1;
            ps[w * 16 + quad * 4 + reg][lm]      = f2bf(p0);
            ps[w * 16 + quad * 4 + reg][16 + lm] = f2bf(p1);
        }

        // ---- PV: P (A layout via LDS, intra-wave) x V^T tiles ----
        const bf16x8 pf = *(bf16x8*)&ps[w * 16 + lm][quad * 8];
#pragma unroll
        for (int nt = 0; nt < 8; ++nt) {
            const bf16x8 vrf = *(bf16x8*)&vt[0][nt * 16 + lm][quad * 8];
            const bf16x8 vif = *(bf16x8*)&vt[1][nt * 16 + lm][quad * 8];
            Or[nt] = MFMA16(pf, vrf, Or[nt]);
            Oi[nt] = MFMA16(pf, vif, Oi[nt]);
        }
    }

    // ---- finalize: reduce l across 16-lane group, scale, store ----
    float linv[4];
#pragma unroll
    for (int reg = 0; reg < 4; ++reg) {
        float l = l_st[reg];
#pragma unroll
        for (int off = 1; off < 16; off <<= 1) l += __shfl_xor(l, off);
        linv[reg] = 1.f / l;
    }
    const long ob = hbase + (long)(q0 + w * 16) * DD;
#pragma unroll
    for (int nt = 0; nt < 8; ++nt) {
        const int c = nt * 16 + lm;
#pragma unroll
        for (int reg = 0; reg < 4; ++reg) {
            const long R = ob + (long)(quad * 4 + reg) * DD + c;
            out_r[R] = Or[nt][reg] * linv[reg];
            out_i[R] = Oi[nt][reg] * linv[reg];
        }
    }
}

// ---------------------------------------------------------------------------
extern "C" void kernel_launch(void* const* d_in, const int* in_sizes, int n_in,
                              void* d_out, int out_size, void* d_ws, size_t ws_size,
                              hipStream_t stream) {
    const float* q_r    = (const float*)d_in[0];
    const float* q_i    = (const float*)d_in[1];
    const float* k_r    = (const float*)d_in[2];
    const float* k_i    = (const float*)d_in[3];
    const float* v_r    = (const float*)d_in[4];
    const float* v_i    = (const float*)d_in[5];
    const float* pe_q_r = (const float*)d_in[6];
    const float* pe_q_i = (const float*)d_in[7];
    const float* pe_k_r = (const float*)d_in[8];
    const float* pe_k_i = (const float*)d_in[9];
    const float* qw_r = (const float*)d_in[10];
    const float* qw_i = (const float*)d_in[11];
    const float* qb_r = (const float*)d_in[12];
    const float* qb_i = (const float*)d_in[13];
    const float* kw_r = (const float*)d_in[14];
    const float* kw_i = (const float*)d_in[15];
    const float* kb_r = (const float*)d_in[16];
    const float* kb_i = (const float*)d_in[17];
    const float* vw_r = (const float*)d_in[18];
    const float* vw_i = (const float*)d_in[19];
    const float* vb_r = (const float*)d_in[20];
    const float* vb_i = (const float*)d_in[21];
    const float* gw_r = (const float*)d_in[22];
    const float* gw_i = (const float*)d_in[23];
    const float* gb_r = (const float*)d_in[24];
    const float* gb_i = (const float*)d_in[25];
    const float* ow_r = (const float*)d_in[26];
    const float* ow_i = (const float*)d_in[27];
    const float* ob_r = (const float*)d_in[28];
    const float* ob_i = (const float*)d_in[29];

    float* out_r = (float*)d_out;              // attn a_r temp, then final out_r
    float* out_i = out_r + (long)OUTSZ;
    float* g_r   = out_r + 2L * OUTSZ;
    float* g_i   = out_r + 3L * OUTSZ;

    unsigned short* ws = (unsigned short*)d_ws; // 6 x 8 MiB bf16
    unsigned short* pqr = ws + 0L * OUTSZ;
    unsigned short* pqi = ws + 1L * OUTSZ;
    unsigned short* pkr = ws + 2L * OUTSZ;
    unsigned short* pki = ws + 3L * OUTSZ;
    unsigned short* pvr = ws + 4L * OUTSZ;
    unsigned short* pvi = ws + 5L * OUTSZ;

    const dim3 blk(512);

    ClinPtrs P0 = {q_r, q_i, nullptr, nullptr, qw_r, qw_i, qb_r, qb_i,
                   pe_q_r, pe_q_i, pqr, pqi, 1};
    ClinPtrs P1 = {k_r, k_i, nullptr, nullptr, kw_r, kw_i, kb_r, kb_i,
                   pe_k_r, pe_k_i, pkr, pki, 1};
    ClinPtrs P2 = {v_r, v_i, nullptr, nullptr, vw_r, vw_i, vb_r, vb_i,
                   nullptr, nullptr, pvr, pvi, 1};
    ClinPtrs P3 = {q_r, q_i, nullptr, nullptr, gw_r, gw_i, gb_r, gb_i,
                   nullptr, nullptr, g_r, g_i, 0};

    // all 4 projections in one launch: grid (256 row-blocks, 4 projections)
    clin_mfma<false><<<dim3(NROWS / 128, 4), blk, 0, stream>>>(P0, P1, P2, P3);

    // flash attention -> a_r, a_i parked in d_out slots 0,1
    attn_mfma<<<dim3((SS / 128) * HH), blk, 0, stream>>>(
        pqr, pqi, pkr, pki, pvr, pvi, out_r, out_i);

    // gate + o-projection, in-place over d_out slots 0,1 (wave-disjoint rows)
    ClinPtrs PF = {g_r, g_i, out_r, out_i, ow_r, ow_i, ob_r, ob_i,
                   nullptr, nullptr, out_r, out_i, 0};
    clin_mfma<true><<<dim3(NROWS / 128, 1), blk, 0, stream>>>(PF, PF, PF, PF);
}